// Round 1
// baseline (211.813 us; speedup 1.0000x reference)
//
#include <hip/hip_runtime.h>
#include <hip/hip_bf16.h>

// Problem constants
#define N_   4
#define C_   64
#define CI_  16
#define H_   96
#define W__  96
#define PS_  7
#define S0_  4
#define WS_  9
#define K_   32
#define WH_  4      // WS/2
#define PP_  3      // PS/2
#define PAD_ 7      // WH+PP
#define nH_  24     // H/S0
#define NQ_  576    // nH*nH
#define D_   784    // CI*PS*PS
#define HP_  110    // H + 2*PAD
#define HW_  9216   // H*W
#define HPW_ 12100  // HP*HP

// ---------------------------------------------------------------------------
// K1: fused 1x1 convs (theta/phi/g) computed directly at reflect-padded
// coordinates -> theta_p, phi_p, g_p each (N, CI, 110, 110)
// ---------------------------------------------------------------------------
__global__ __launch_bounds__(256) void conv_pad_kernel(
    const float* __restrict__ vid,
    const float* __restrict__ tw, const float* __restrict__ tb,
    const float* __restrict__ pw, const float* __restrict__ pb,
    const float* __restrict__ gw, const float* __restrict__ gb,
    float* __restrict__ theta_p, float* __restrict__ phi_p,
    float* __restrict__ g_p)
{
    __shared__ float w_lds[3][CI_][C_];
    __shared__ float b_lds[3][CI_];
    int tid = threadIdx.x;
    for (int i = tid; i < CI_ * C_; i += 256) {
        w_lds[0][i >> 6][i & 63] = tw[i];
        w_lds[1][i >> 6][i & 63] = pw[i];
        w_lds[2][i >> 6][i & 63] = gw[i];
    }
    if (tid < CI_) {
        b_lds[0][tid] = tb[tid];
        b_lds[1][tid] = pb[tid];
        b_lds[2][tid] = gb[tid];
    }
    __syncthreads();

    int idx = blockIdx.x * 256 + tid;
    if (idx >= N_ * HP_ * HP_) return;
    int xp = idx % HP_;
    int t2 = idx / HP_;
    int yp = t2 % HP_;
    int n  = t2 / HP_;
    // reflect (jnp 'reflect': no edge duplication)
    int y = yp - PAD_; y = (y < 0) ? -y : ((y > H_ - 1) ? 2 * (H_ - 1) - y : y);
    int x = xp - PAD_; x = (x < 0) ? -x : ((x > W__ - 1) ? 2 * (W__ - 1) - x : x);

    float acc[48];
#pragma unroll
    for (int o = 0; o < 48; o++) acc[o] = 0.f;

    const float* vp = vid + (size_t)n * C_ * HW_ + y * W__ + x;
    for (int c = 0; c < C_; c++) {
        float v = vp[c * HW_];
#pragma unroll
        for (int o = 0; o < CI_; o++) {
            acc[o]          += w_lds[0][o][c] * v;
            acc[CI_ + o]    += w_lds[1][o][c] * v;
            acc[2 * CI_ + o]+= w_lds[2][o][c] * v;
        }
    }
    size_t base = (size_t)n * CI_ * HPW_ + yp * HP_ + xp;
#pragma unroll
    for (int o = 0; o < CI_; o++) {
        theta_p[base + (size_t)o * HPW_] = acc[o]           + b_lds[0][o];
        phi_p  [base + (size_t)o * HPW_] = acc[CI_ + o]     + b_lds[1][o];
        g_p    [base + (size_t)o * HPW_] = acc[2 * CI_ + o] + b_lds[2][o];
    }
}

// ---------------------------------------------------------------------------
// K2: per (n,q): stage Q patch + phi/g candidate regions in LDS, compute
// 81 distances, top-32 (exact lexicographic rank like jax top_k), softmax,
// weighted g-patch sum -> outp (N*NQ, 784)
// ---------------------------------------------------------------------------
__global__ __launch_bounds__(128) void attn_kernel(
    const float* __restrict__ theta_p, const float* __restrict__ phi_p,
    const float* __restrict__ g_p, const int* __restrict__ flows,
    float* __restrict__ outp)
{
    __shared__ float Q[CI_][PS_][PS_];        // 784 f
    __shared__ float P[CI_][15][15];          // 3600 f
    __shared__ float G[CI_][15][15];          // 3600 f
    __shared__ float dist[81];
    __shared__ int   selflag[81];
    __shared__ float wlist[K_];
    __shared__ int   cilist[K_], cjlist[K_];
    __shared__ float dmin_s, esum_s;

    int tid = threadIdx.x;
    int bq  = blockIdx.x;            // n*NQ + q
    int n = bq / NQ_, q = bq % NQ_;
    int qi = q / nH_, qj = q % nH_;
    int qci = qi * S0_, qcj = qj * S0_;

    int f0 = flows[((n * 2 + 0) * H_ + qci) * W__ + qcj];
    int f1 = flows[((n * 2 + 1) * H_ + qci) * W__ + qcj];
    int bi = qci + f0, bj = qcj + f1;
    int loi = min(max(bi - WH_, 0), H_ - 1);
    int hii = min(max(bi + WH_, 0), H_ - 1);
    int loj = min(max(bj - WH_, 0), W__ - 1);
    int hij = min(max(bj + WH_, 0), W__ - 1);
    int Ri = hii - loi + PS_;        // <= 15
    int Rj = hij - loj + PS_;        // <= 15

    const size_t npbase = (size_t)n * CI_ * HPW_;

    // stage Q patch (centered at query, padded coords rows qci+4 .. qci+10)
    for (int i = tid; i < D_; i += 128) {
        int c = i / 49, r = (i / 7) % 7, s = i % 7;
        Q[c][r][s] = theta_p[npbase + (size_t)c * HPW_ +
                             (qci + WH_ + r) * HP_ + (qcj + WH_ + s)];
    }
    // stage phi & g regions
    int tot = CI_ * Ri * Rj;
    for (int i = tid; i < tot; i += 128) {
        int c = i / (Ri * Rj), rem = i % (Ri * Rj);
        int r = rem / Rj, s = rem % Rj;
        size_t gi = npbase + (size_t)c * HPW_ +
                    (loi + WH_ + r) * HP_ + (loj + WH_ + s);
        P[c][r][s] = phi_p[gi];
        G[c][r][s] = g_p[gi];
    }
    if (tid == 0) esum_s = 0.f;
    __syncthreads();

    int ci = 0, cj = 0;
    if (tid < 81) {
        int wi = tid / WS_, wj = tid % WS_;
        ci = min(max(bi + wi - WH_, 0), H_ - 1) - loi;   // local center row
        cj = min(max(bj + wj - WH_, 0), W__ - 1) - loj;  // local center col
        float d = 0.f;
        for (int c = 0; c < CI_; c++) {
#pragma unroll
            for (int r = 0; r < PS_; r++) {
#pragma unroll
                for (int s = 0; s < PS_; s++) {
                    float df = Q[c][r][s] - P[c][ci + r][cj + s];
                    d += df * df;
                }
            }
        }
        dist[tid] = d;
    }
    __syncthreads();

    if (tid < 81) {
        float d = dist[tid];
        int rank = 0;
        for (int j = 0; j < 81; j++) {
            float dj = dist[j];
            rank += (dj < d) || (dj == d && j < tid);
        }
        selflag[tid] = (rank < K_) ? 1 : 0;
        if (rank == 0) dmin_s = d;
    }
    __syncthreads();

    float e = 0.f;
    int pos = -1;
    if (tid < 81 && selflag[tid]) {
        pos = 0;
        for (int j = 0; j < tid; j++) pos += selflag[j];
        e = expf(10.f * (dmin_s - dist[tid]));   // softmax(SCALE*negd), max-shifted
        atomicAdd(&esum_s, e);
    }
    __syncthreads();
    if (pos >= 0) {
        wlist[pos]  = e / esum_s;
        cilist[pos] = ci;
        cjlist[pos] = cj;
    }
    __syncthreads();

    float* op = outp + (size_t)bq * D_;
    for (int dIdx = tid; dIdx < D_; dIdx += 128) {
        int c = dIdx / 49, r = (dIdx / 7) % 7, s = dIdx % 7;
        float acc = 0.f;
#pragma unroll
        for (int k = 0; k < K_; k++) {
            acc += wlist[k] * G[c][cilist[k] + r][cjlist[k] + s];
        }
        op[dIdx] = acc;
    }
}

// ---------------------------------------------------------------------------
// K3: per output pixel: gather <=2x2 contributing query patch values,
// divide by analytic count, fused 16->64 conv + bias + residual.
// ---------------------------------------------------------------------------
__global__ __launch_bounds__(256) void output_kernel(
    const float* __restrict__ vid, const float* __restrict__ outp,
    const float* __restrict__ ww, const float* __restrict__ wb,
    float* __restrict__ out)
{
    __shared__ float w_lds[C_][CI_];   // (64,16)
    __shared__ float b_lds[C_];
    int tid = threadIdx.x;
    for (int i = tid; i < C_ * CI_; i += 256) w_lds[i / CI_][i % CI_] = ww[i];
    if (tid < C_) b_lds[tid] = wb[tid];
    __syncthreads();

    int idx = blockIdx.x * 256 + tid;
    if (idx >= N_ * H_ * W__) return;
    int x = idx % W__;
    int t2 = idx / W__;
    int y = t2 % H_;
    int n = t2 / H_;

    // contributing query grid rows: qci = 4*t with y-3 <= qci <= y+3
    int tlo_i = y >> 2;
    int thi_i = min(nH_ - 1, (y + PP_) >> 2);
    int tlo_j = x >> 2;
    int thi_j = min(nH_ - 1, (x + PP_) >> 2);
    int ni = thi_i - tlo_i + 1;
    int nj = thi_j - tlo_j + 1;
    float inv = 1.f / (float)(ni * nj);

    float agg[CI_];
#pragma unroll
    for (int c = 0; c < CI_; c++) agg[c] = 0.f;

    for (int ii = 0; ii < ni; ii++) {
        int qi = tlo_i + ii;
        int a = y + PP_ - S0_ * qi;            // 0..6
        for (int jj = 0; jj < nj; jj++) {
            int qj = tlo_j + jj;
            int b = x + PP_ - S0_ * qj;        // 0..6
            const float* op = outp + ((size_t)n * NQ_ + qi * nH_ + qj) * D_ + a * 7 + b;
#pragma unroll
            for (int c = 0; c < CI_; c++) agg[c] += op[c * 49];
        }
    }
#pragma unroll
    for (int c = 0; c < CI_; c++) agg[c] *= inv;

    const float* vp = vid + (size_t)n * C_ * HW_ + y * W__ + x;
    float* op2 = out + (size_t)n * C_ * HW_ + y * W__ + x;
#pragma unroll
    for (int co = 0; co < C_; co++) {
        float o = b_lds[co];
#pragma unroll
        for (int c = 0; c < CI_; c++) o += w_lds[co][c] * agg[c];
        op2[(size_t)co * HW_] = vp[(size_t)co * HW_] + o;
    }
}

// ---------------------------------------------------------------------------
extern "C" void kernel_launch(void* const* d_in, const int* in_sizes, int n_in,
                              void* d_out, int out_size, void* d_ws, size_t ws_size,
                              hipStream_t stream) {
    const float* vid   = (const float*)d_in[0];
    const int*   flows = (const int*)  d_in[1];
    const float* tw    = (const float*)d_in[2];
    const float* tb    = (const float*)d_in[3];
    const float* pw    = (const float*)d_in[4];
    const float* pb    = (const float*)d_in[5];
    const float* gw    = (const float*)d_in[6];
    const float* gb    = (const float*)d_in[7];
    const float* ww    = (const float*)d_in[8];
    const float* wb    = (const float*)d_in[9];
    float* out = (float*)d_out;

    float* ws = (float*)d_ws;
    const size_t padsz = (size_t)N_ * CI_ * HPW_;       // 774,400 floats
    float* theta_p = ws;
    float* phi_p   = ws + padsz;
    float* g_p     = ws + 2 * padsz;
    float* outp    = ws + 3 * padsz;                    // N*NQ*784 = 1,806,336 f
    // total ws use: ~16.5 MB

    {
        int tot = N_ * HP_ * HP_;
        conv_pad_kernel<<<(tot + 255) / 256, 256, 0, stream>>>(
            vid, tw, tb, pw, pb, gw, gb, theta_p, phi_p, g_p);
    }
    attn_kernel<<<N_ * NQ_, 128, 0, stream>>>(theta_p, phi_p, g_p, flows, outp);
    {
        int tot = N_ * H_ * W__;
        output_kernel<<<(tot + 255) / 256, 256, 0, stream>>>(vid, outp, ww, wb, out);
    }
}

// Round 3
// 179.918 us; speedup vs baseline: 1.1773x; 1.1773x over previous
//
#include <hip/hip_runtime.h>
#include <hip/hip_bf16.h>

// Problem constants
#define N_   4
#define C_   64
#define CI_  16
#define H_   96
#define W__  96
#define PS_  7
#define S0_  4
#define WS_  9
#define K_   32
#define WH_  4      // WS/2
#define PP_  3      // PS/2
#define nH_  24     // H/S0
#define NQ_  576    // nH*nH
#define D_   784    // CI*PS*PS
#define HW_  9216   // H*W

#define PLS  226    // P/G LDS plane stride (225 -> 226; 226 % 32 == 2 -> 2-way-free banks)
#define QLS  52     // Q LDS channel stride (49 -> 52 for float4 alignment)

__device__ __forceinline__ int rf(int v) {
    v = v < 0 ? -v : v;
    return v > H_ - 1 ? 2 * (H_ - 1) - v : v;
}

// ---------------------------------------------------------------------------
// K1: fused 1x1 convs on the 96x96 grid only (no pad materialization).
// Weights read with block-uniform indices -> compiler emits s_load into SGPRs
// (v_fma with SGPR operand), no LDS. Output channels-last: [n][y][x][c].
// ---------------------------------------------------------------------------
__global__ __launch_bounds__(64) void conv_kernel(
    const float* __restrict__ vid,
    const float* __restrict__ tw, const float* __restrict__ tb,
    const float* __restrict__ pw, const float* __restrict__ pb,
    const float* __restrict__ gw, const float* __restrict__ gb,
    float* __restrict__ theta, float* __restrict__ phi, float* __restrict__ g)
{
    int idx = blockIdx.x * 64 + threadIdx.x;
    if (idx >= N_ * HW_) return;
    int n = idx / HW_, pix = idx % HW_;
    const float* vp = vid + (size_t)n * C_ * HW_ + pix;

    float acc[48];
#pragma unroll
    for (int o = 0; o < 48; o++) acc[o] = 0.f;

    for (int c = 0; c < C_; c += 4) {
        float v0 = vp[(c + 0) * HW_];
        float v1 = vp[(c + 1) * HW_];
        float v2 = vp[(c + 2) * HW_];
        float v3 = vp[(c + 3) * HW_];
#pragma unroll
        for (int o = 0; o < CI_; o++) {
            float4 a = *(const float4*)&tw[o * C_ + c];   // uniform -> s_load
            acc[o]      += a.x * v0 + a.y * v1 + a.z * v2 + a.w * v3;
            float4 b = *(const float4*)&pw[o * C_ + c];
            acc[16 + o] += b.x * v0 + b.y * v1 + b.z * v2 + b.w * v3;
            float4 cc = *(const float4*)&gw[o * C_ + c];
            acc[32 + o] += cc.x * v0 + cc.y * v1 + cc.z * v2 + cc.w * v3;
        }
    }

    size_t ob = ((size_t)n * HW_ + pix) * CI_;
#pragma unroll
    for (int o = 0; o < CI_; o += 4) {
        *(float4*)&theta[ob + o] = make_float4(acc[o] + tb[o], acc[o+1] + tb[o+1],
                                               acc[o+2] + tb[o+2], acc[o+3] + tb[o+3]);
        *(float4*)&phi[ob + o]   = make_float4(acc[16+o] + pb[o], acc[16+o+1] + pb[o+1],
                                               acc[16+o+2] + pb[o+2], acc[16+o+3] + pb[o+3]);
        *(float4*)&g[ob + o]     = make_float4(acc[32+o] + gb[o], acc[32+o+1] + gb[o+1],
                                               acc[32+o+2] + gb[o+2], acc[32+o+3] + gb[o+3]);
    }
}

// ---------------------------------------------------------------------------
// K2: per (n,q). 192 threads.
//  Phase A: stage Q patch + full 15x15 phi/g regions (reflect-mapped, float4
//           loads from channels-last arrays).
//  Phase B: 144 lanes = (c 0..15, cj 0..8): sliding-window correlation with
//           Q-channel in 49 registers; per lane ~150 LDS ops instead of 1568.
//           dist' = |P_win|^2 - 2*Q.P  (|Q|^2 cancels in top-k & softmax).
//  Phase C: exact stable top-32 rank, softmax, weighted G-patch sum.
// ---------------------------------------------------------------------------
__global__ __launch_bounds__(192) void attn_kernel(
    const float* __restrict__ theta, const float* __restrict__ phi,
    const float* __restrict__ g, const int* __restrict__ flows,
    float* __restrict__ outp)
{
    __shared__ float Ql[CI_ * QLS];        // 832 f
    __shared__ float Pl[CI_ * PLS];        // 3616 f
    __shared__ float Gl[CI_ * PLS];        // 3616 f
    __shared__ float part[81 * 17];        // 1377 f  (stride 17 vs bank conflicts)
    __shared__ float dist[81];
    __shared__ int   selflag[81];
    __shared__ float wlist[K_];
    __shared__ int   cilist[K_], cjlist[K_];
    __shared__ float dmin_s, esum_s;

    int tid = threadIdx.x;
    int bq  = blockIdx.x;
    int n = bq / NQ_, q0 = bq % NQ_;
    int qi = q0 / nH_, qj = q0 % nH_;
    int qci = qi * S0_, qcj = qj * S0_;

    int f0 = flows[((n * 2 + 0) * H_ + qci) * W__ + qcj];
    int f1 = flows[((n * 2 + 1) * H_ + qci) * W__ + qcj];
    int bi = qci + f0, bj = qcj + f1;
    int loi = min(max(bi - WH_, 0), H_ - 1);
    int loj = min(max(bj - WH_, 0), W__ - 1);

    const float* thn = theta + (size_t)n * HW_ * CI_;
    const float* phn = phi   + (size_t)n * HW_ * CI_;
    const float* gn  = g     + (size_t)n * HW_ * CI_;

    // ---- Phase A: staging ----
    for (int i = tid; i < 49 * 4; i += 192) {           // Q: 49 px x 4 c-groups
        int px = i >> 2, cg = (i & 3) * 4;
        int r = px / 7, s = px % 7;
        size_t gb = ((size_t)(rf(qci + r - PP_) * W__ + rf(qcj + s - PP_))) * CI_ + cg;
        float4 v = *(const float4*)&thn[gb];
        Ql[(cg + 0) * QLS + px] = v.x;
        Ql[(cg + 1) * QLS + px] = v.y;
        Ql[(cg + 2) * QLS + px] = v.z;
        Ql[(cg + 3) * QLS + px] = v.w;
    }
    for (int i = tid; i < 225 * 4; i += 192) {          // P,G: 225 px x 4 c-groups
        int px = i >> 2, cg = (i & 3) * 4;
        int r = px / 15, s = px % 15;
        size_t gb = ((size_t)(rf(loi + r - PP_) * W__ + rf(loj + s - PP_))) * CI_ + cg;
        float4 pv = *(const float4*)&phn[gb];
        float4 gv = *(const float4*)&gn[gb];
        Pl[(cg + 0) * PLS + px] = pv.x;
        Pl[(cg + 1) * PLS + px] = pv.y;
        Pl[(cg + 2) * PLS + px] = pv.z;
        Pl[(cg + 3) * PLS + px] = pv.w;
        Gl[(cg + 0) * PLS + px] = gv.x;
        Gl[(cg + 1) * PLS + px] = gv.y;
        Gl[(cg + 2) * PLS + px] = gv.z;
        Gl[(cg + 3) * PLS + px] = gv.w;
    }
    if (tid == 0) esum_s = 0.f;
    __syncthreads();

    // ---- Phase B: per-(c,cj) sliding correlation ----
    if (tid < 144) {
        int c  = tid & 15;
        int cj = tid >> 4;                 // 0..8
        float qr[49];
#pragma unroll
        for (int i = 0; i < 12; i++) {
            float4 t4 = *(const float4*)&Ql[c * QLS + i * 4];
            qr[i * 4 + 0] = t4.x; qr[i * 4 + 1] = t4.y;
            qr[i * 4 + 2] = t4.z; qr[i * 4 + 3] = t4.w;
        }
        qr[48] = Ql[c * QLS + 48];

        float corr[9], sqv[9];
#pragma unroll
        for (int i = 0; i < 9; i++) { corr[i] = 0.f; sqv[i] = 0.f; }

        const float* Pb = &Pl[c * PLS + cj];
#pragma unroll
        for (int y = 0; y < 15; y++) {
            float seg[7];
#pragma unroll
            for (int s = 0; s < 7; s++) seg[s] = Pb[y * 15 + s];
            float s2 = 0.f;
#pragma unroll
            for (int s = 0; s < 7; s++) s2 += seg[s] * seg[s];
#pragma unroll
            for (int ci = 0; ci < 9; ci++) {
                if (y - ci >= 0 && y - ci < 7) {       // compile-time per (y,ci)
                    const int r = y - ci;
                    float t = 0.f;
#pragma unroll
                    for (int s = 0; s < 7; s++) t += qr[r * 7 + s] * seg[s];
                    corr[ci] += t;
                    sqv[ci]  += s2;
                }
            }
        }
#pragma unroll
        for (int ci = 0; ci < 9; ci++)
            part[(cj * 9 + ci) * 17 + c] = sqv[ci] - 2.f * corr[ci];
    }
    __syncthreads();

    // ---- Phase C1: reduce over channels per window ----
    if (tid < 81) {
        int wi = tid / WS_, wj = tid % WS_;
        int cil = min(max(bi + wi - WH_, 0), H_ - 1) - loi;
        int cjl = min(max(bj + wj - WH_, 0), W__ - 1) - loj;
        int pidx = cjl * 9 + cil;
        float d = 0.f;
#pragma unroll
        for (int c = 0; c < CI_; c++) d += part[pidx * 17 + c];
        dist[tid] = d;
    }
    __syncthreads();

    // ---- Phase C2: stable top-K rank (matches jax.lax.top_k tie-break) ----
    if (tid < 81) {
        float d = dist[tid];
        int rank = 0;
        for (int j = 0; j < 81; j++) {
            float dj = dist[j];
            rank += (dj < d) || (dj == d && j < tid);
        }
        selflag[tid] = (rank < K_) ? 1 : 0;
        if (rank == 0) dmin_s = d;
    }
    __syncthreads();

    float e = 0.f;
    int pos = -1;
    if (tid < 81 && selflag[tid]) {
        pos = 0;
        for (int j = 0; j < tid; j++) pos += selflag[j];
        e = expf(10.f * (dmin_s - dist[tid]));
        atomicAdd(&esum_s, e);
    }
    __syncthreads();
    if (pos >= 0) {
        int wi = tid / WS_, wj = tid % WS_;
        wlist[pos]  = e / esum_s;
        cilist[pos] = min(max(bi + wi - WH_, 0), H_ - 1) - loi;
        cjlist[pos] = min(max(bj + wj - WH_, 0), W__ - 1) - loj;
    }
    __syncthreads();

    // ---- Phase C3: weighted G-patch sum ----
    float wreg[K_];
    int   oreg[K_];
#pragma unroll
    for (int k = 0; k < K_; k++) {
        wreg[k] = wlist[k];
        oreg[k] = cilist[k] * 15 + cjlist[k];
    }
    float* op = outp + (size_t)bq * D_;
    for (int dI = tid; dI < D_; dI += 192) {
        int c = dI / 49, rs = dI % 49, r = rs / 7, s = rs % 7;
        const float* Gb = &Gl[c * PLS + r * 15 + s];
        float acc = 0.f;
#pragma unroll
        for (int k = 0; k < K_; k++) acc += wreg[k] * Gb[oreg[k]];
        op[dI] = acc;
    }
}

// ---------------------------------------------------------------------------
// K3: per output pixel: gather <=2x2 contributing query patch values,
// divide by analytic count, fused 16->64 conv (uniform s_load weights)
// + bias + residual.
// ---------------------------------------------------------------------------
__global__ __launch_bounds__(64) void output_kernel(
    const float* __restrict__ vid, const float* __restrict__ outp,
    const float* __restrict__ ww, const float* __restrict__ wb,
    float* __restrict__ out)
{
    int idx = blockIdx.x * 64 + threadIdx.x;
    if (idx >= N_ * HW_) return;
    int x = idx % W__;
    int t2 = idx / W__;
    int y = t2 % H_;
    int n = t2 / H_;

    int tlo_i = y >> 2;
    int thi_i = min(nH_ - 1, (y + PP_) >> 2);
    int tlo_j = x >> 2;
    int thi_j = min(nH_ - 1, (x + PP_) >> 2);
    int ni = thi_i - tlo_i + 1;
    int nj = thi_j - tlo_j + 1;
    float inv = 1.f / (float)(ni * nj);

    float agg[CI_];
#pragma unroll
    for (int c = 0; c < CI_; c++) agg[c] = 0.f;

    for (int ii = 0; ii < ni; ii++) {
        int qi = tlo_i + ii;
        int a = y + PP_ - S0_ * qi;            // 0..6
        for (int jj = 0; jj < nj; jj++) {
            int qj = tlo_j + jj;
            int b = x + PP_ - S0_ * qj;        // 0..6
            const float* op = outp + ((size_t)n * NQ_ + qi * nH_ + qj) * D_ + a * 7 + b;
#pragma unroll
            for (int c = 0; c < CI_; c++) agg[c] += op[c * 49];
        }
    }
#pragma unroll
    for (int c = 0; c < CI_; c++) agg[c] *= inv;

    const float* vp = vid + (size_t)n * C_ * HW_ + y * W__ + x;
    float* op2 = out + (size_t)n * C_ * HW_ + y * W__ + x;
#pragma unroll
    for (int co = 0; co < C_; co++) {
        float4 w0 = *(const float4*)&ww[co * CI_ + 0];   // uniform -> s_load
        float4 w1 = *(const float4*)&ww[co * CI_ + 4];
        float4 w2 = *(const float4*)&ww[co * CI_ + 8];
        float4 w3 = *(const float4*)&ww[co * CI_ + 12];
        float o = wb[co];
        o += w0.x * agg[0]  + w0.y * agg[1]  + w0.z * agg[2]  + w0.w * agg[3];
        o += w1.x * agg[4]  + w1.y * agg[5]  + w1.z * agg[6]  + w1.w * agg[7];
        o += w2.x * agg[8]  + w2.y * agg[9]  + w2.z * agg[10] + w2.w * agg[11];
        o += w3.x * agg[12] + w3.y * agg[13] + w3.z * agg[14] + w3.w * agg[15];
        op2[(size_t)co * HW_] = vp[(size_t)co * HW_] + o;
    }
}

// ---------------------------------------------------------------------------
extern "C" void kernel_launch(void* const* d_in, const int* in_sizes, int n_in,
                              void* d_out, int out_size, void* d_ws, size_t ws_size,
                              hipStream_t stream) {
    const float* vid   = (const float*)d_in[0];
    const int*   flows = (const int*)  d_in[1];
    const float* tw    = (const float*)d_in[2];
    const float* tb    = (const float*)d_in[3];
    const float* pw    = (const float*)d_in[4];
    const float* pb    = (const float*)d_in[5];
    const float* gw    = (const float*)d_in[6];
    const float* gb    = (const float*)d_in[7];
    const float* ww    = (const float*)d_in[8];
    const float* wb    = (const float*)d_in[9];
    float* out = (float*)d_out;

    float* ws = (float*)d_ws;
    const size_t fsz = (size_t)N_ * HW_ * CI_;          // 589,824 floats each
    float* theta = ws;
    float* phi   = ws + fsz;
    float* g     = ws + 2 * fsz;
    float* outp  = ws + 3 * fsz;                        // N*NQ*784 = 1,806,336 f

    {
        int tot = N_ * HW_;
        conv_kernel<<<(tot + 63) / 64, 64, 0, stream>>>(
            vid, tw, tb, pw, pb, gw, gb, theta, phi, g);
    }
    attn_kernel<<<N_ * NQ_, 192, 0, stream>>>(theta, phi, g, flows, outp);
    {
        int tot = N_ * HW_;
        output_kernel<<<(tot + 63) / 64, 64, 0, stream>>>(vid, outp, ww, wb, out);
    }
}

// Round 4
// 128.725 us; speedup vs baseline: 1.6455x; 1.3977x over previous
//
#include <hip/hip_runtime.h>
#include <hip/hip_bf16.h>

// Problem constants
#define N_   4
#define C_   64
#define CI_  16
#define H_   96
#define W__  96
#define PS_  7
#define S0_  4
#define WS_  9
#define K_   32
#define WH_  4      // WS/2
#define PP_  3      // PS/2
#define nH_  24     // H/S0
#define NQ_  576    // nH*nH
#define D_   784    // CI*PS*PS
#define HW_  9216   // H*W

#define PLS  226    // P/G LDS plane stride (226 % 32 == 2 -> 2-way-free banks)
#define QLS  52     // Q LDS channel stride (49 -> 52 for float4 alignment)

__device__ __forceinline__ int rf(int v) {
    v = v < 0 ? -v : v;
    return v > H_ - 1 ? 2 * (H_ - 1) - v : v;
}

// ---------------------------------------------------------------------------
// K1: fused 1x1 convs as register-blocked GEMM. Thread = (pixel, array,
// 8-output group). 864 blocks x 256 threads = 3456 waves (3.4/SIMD).
// Weights block-uniform -> s_load; 64 vid loads fully unrolled (hoisted);
// 512 FMAs/thread. Output channels-last: [n*HW + pix][16].
// ---------------------------------------------------------------------------
__global__ __launch_bounds__(256) void conv_kernel(
    const float* __restrict__ vid,
    const float* __restrict__ tw, const float* __restrict__ tb,
    const float* __restrict__ pw, const float* __restrict__ pb,
    const float* __restrict__ gw, const float* __restrict__ gb,
    float* __restrict__ theta, float* __restrict__ phi, float* __restrict__ g)
{
    int b = blockIdx.x;
    int pbk = b % 144;            // 144 pixel-blocks of 256 pixels
    int t2  = b / 144;
    int og  = t2 & 1;             // output half: 0 -> ch 0..7, 1 -> ch 8..15
    int arr = t2 >> 1;            // 0=theta 1=phi 2=g
    const float* wsel = arr == 0 ? tw : (arr == 1 ? pw : gw);
    const float* bsel = arr == 0 ? tb : (arr == 1 ? pb : gb);
    float*       dsel = arr == 0 ? theta : (arr == 1 ? phi : g);

    int idx = pbk * 256 + threadIdx.x;       // global pixel in [0, N*HW)
    int n = idx / HW_, pix = idx % HW_;
    const float* vp = vid + (size_t)n * C_ * HW_ + pix;
    const float* wp = wsel + og * 8 * C_;

    float acc[8];
#pragma unroll
    for (int o = 0; o < 8; o++) acc[o] = 0.f;

#pragma unroll
    for (int cc = 0; cc < C_; cc += 8) {
        float v[8];
#pragma unroll
        for (int j = 0; j < 8; j++) v[j] = vp[(cc + j) * HW_];
#pragma unroll
        for (int o = 0; o < 8; o++) {
            float4 wa = *(const float4*)&wp[o * C_ + cc];       // uniform -> s_load
            float4 wbv = *(const float4*)&wp[o * C_ + cc + 4];
            acc[o] += wa.x * v[0] + wa.y * v[1] + wa.z * v[2] + wa.w * v[3]
                    + wbv.x * v[4] + wbv.y * v[5] + wbv.z * v[6] + wbv.w * v[7];
        }
    }

    size_t ob = (size_t)idx * CI_ + og * 8;
    *(float4*)&dsel[ob + 0] = make_float4(acc[0] + bsel[og * 8 + 0],
                                          acc[1] + bsel[og * 8 + 1],
                                          acc[2] + bsel[og * 8 + 2],
                                          acc[3] + bsel[og * 8 + 3]);
    *(float4*)&dsel[ob + 4] = make_float4(acc[4] + bsel[og * 8 + 4],
                                          acc[5] + bsel[og * 8 + 5],
                                          acc[6] + bsel[og * 8 + 6],
                                          acc[7] + bsel[og * 8 + 7]);
}

// ---------------------------------------------------------------------------
// K2: per (n,q). 192 threads. Same structure as round-2 (was sub-top):
//  A: stage Q patch + 15x15 phi/g regions (float4, channels-last).
//  B: 144 lanes (c,cj): sliding-window correlation, Q in regs.
//  C: stable top-32 rank, softmax, weighted G sum.
// Output layout CHANGED to [n*NQ+q][49 patch-px][16 c] so K3 gathers
// 16 contiguous floats per contribution.
// ---------------------------------------------------------------------------
__global__ __launch_bounds__(192) void attn_kernel(
    const float* __restrict__ theta, const float* __restrict__ phi,
    const float* __restrict__ g, const int* __restrict__ flows,
    float* __restrict__ outp)
{
    __shared__ float Ql[CI_ * QLS];        // 832 f
    __shared__ float Pl[CI_ * PLS];        // 3616 f
    __shared__ float Gl[CI_ * PLS];        // 3616 f
    __shared__ float part[81 * 17];
    __shared__ float dist[81];
    __shared__ int   selflag[81];
    __shared__ float wlist[K_];
    __shared__ int   cilist[K_], cjlist[K_];
    __shared__ float dmin_s, esum_s;

    int tid = threadIdx.x;
    int bq  = blockIdx.x;
    int n = bq / NQ_, q0 = bq % NQ_;
    int qi = q0 / nH_, qj = q0 % nH_;
    int qci = qi * S0_, qcj = qj * S0_;

    int f0 = flows[((n * 2 + 0) * H_ + qci) * W__ + qcj];
    int f1 = flows[((n * 2 + 1) * H_ + qci) * W__ + qcj];
    int bi = qci + f0, bj = qcj + f1;
    int loi = min(max(bi - WH_, 0), H_ - 1);
    int loj = min(max(bj - WH_, 0), W__ - 1);

    const float* thn = theta + (size_t)n * HW_ * CI_;
    const float* phn = phi   + (size_t)n * HW_ * CI_;
    const float* gn  = g     + (size_t)n * HW_ * CI_;

    // ---- Phase A: staging ----
    for (int i = tid; i < 49 * 4; i += 192) {
        int px = i >> 2, cg = (i & 3) * 4;
        int r = px / 7, s = px % 7;
        size_t gb = ((size_t)(rf(qci + r - PP_) * W__ + rf(qcj + s - PP_))) * CI_ + cg;
        float4 v = *(const float4*)&thn[gb];
        Ql[(cg + 0) * QLS + px] = v.x;
        Ql[(cg + 1) * QLS + px] = v.y;
        Ql[(cg + 2) * QLS + px] = v.z;
        Ql[(cg + 3) * QLS + px] = v.w;
    }
    for (int i = tid; i < 225 * 4; i += 192) {
        int px = i >> 2, cg = (i & 3) * 4;
        int r = px / 15, s = px % 15;
        size_t gb = ((size_t)(rf(loi + r - PP_) * W__ + rf(loj + s - PP_))) * CI_ + cg;
        float4 pv = *(const float4*)&phn[gb];
        float4 gv = *(const float4*)&gn[gb];
        Pl[(cg + 0) * PLS + px] = pv.x;
        Pl[(cg + 1) * PLS + px] = pv.y;
        Pl[(cg + 2) * PLS + px] = pv.z;
        Pl[(cg + 3) * PLS + px] = pv.w;
        Gl[(cg + 0) * PLS + px] = gv.x;
        Gl[(cg + 1) * PLS + px] = gv.y;
        Gl[(cg + 2) * PLS + px] = gv.z;
        Gl[(cg + 3) * PLS + px] = gv.w;
    }
    if (tid == 0) esum_s = 0.f;
    __syncthreads();

    // ---- Phase B: per-(c,cj) sliding correlation ----
    if (tid < 144) {
        int c  = tid & 15;
        int cj = tid >> 4;
        float qr[49];
#pragma unroll
        for (int i = 0; i < 12; i++) {
            float4 t4 = *(const float4*)&Ql[c * QLS + i * 4];
            qr[i * 4 + 0] = t4.x; qr[i * 4 + 1] = t4.y;
            qr[i * 4 + 2] = t4.z; qr[i * 4 + 3] = t4.w;
        }
        qr[48] = Ql[c * QLS + 48];

        float corr[9], sqv[9];
#pragma unroll
        for (int i = 0; i < 9; i++) { corr[i] = 0.f; sqv[i] = 0.f; }

        const float* Pb = &Pl[c * PLS + cj];
#pragma unroll
        for (int y = 0; y < 15; y++) {
            float seg[7];
#pragma unroll
            for (int s = 0; s < 7; s++) seg[s] = Pb[y * 15 + s];
            float s2 = 0.f;
#pragma unroll
            for (int s = 0; s < 7; s++) s2 += seg[s] * seg[s];
#pragma unroll
            for (int ci = 0; ci < 9; ci++) {
                if (y - ci >= 0 && y - ci < 7) {
                    const int r = y - ci;
                    float t = 0.f;
#pragma unroll
                    for (int s = 0; s < 7; s++) t += qr[r * 7 + s] * seg[s];
                    corr[ci] += t;
                    sqv[ci]  += s2;
                }
            }
        }
#pragma unroll
        for (int ci = 0; ci < 9; ci++)
            part[(cj * 9 + ci) * 17 + c] = sqv[ci] - 2.f * corr[ci];
    }
    __syncthreads();

    // ---- Phase C1: reduce over channels per window ----
    if (tid < 81) {
        int wi = tid / WS_, wj = tid % WS_;
        int cil = min(max(bi + wi - WH_, 0), H_ - 1) - loi;
        int cjl = min(max(bj + wj - WH_, 0), W__ - 1) - loj;
        int pidx = cjl * 9 + cil;
        float d = 0.f;
#pragma unroll
        for (int c = 0; c < CI_; c++) d += part[pidx * 17 + c];
        dist[tid] = d;
    }
    __syncthreads();

    // ---- Phase C2: stable top-K rank ----
    if (tid < 81) {
        float d = dist[tid];
        int rank = 0;
        for (int j = 0; j < 81; j++) {
            float dj = dist[j];
            rank += (dj < d) || (dj == d && j < tid);
        }
        selflag[tid] = (rank < K_) ? 1 : 0;
        if (rank == 0) dmin_s = d;
    }
    __syncthreads();

    float e = 0.f;
    int pos = -1;
    if (tid < 81 && selflag[tid]) {
        pos = 0;
        for (int j = 0; j < tid; j++) pos += selflag[j];
        e = expf(10.f * (dmin_s - dist[tid]));
        atomicAdd(&esum_s, e);
    }
    __syncthreads();
    if (pos >= 0) {
        int wi = tid / WS_, wj = tid % WS_;
        wlist[pos]  = e / esum_s;
        cilist[pos] = min(max(bi + wi - WH_, 0), H_ - 1) - loi;
        cjlist[pos] = min(max(bj + wj - WH_, 0), W__ - 1) - loj;
    }
    __syncthreads();

    // ---- Phase C3: weighted G-patch sum; layout [rs(49)][c(16)] ----
    float wreg[K_];
    int   oreg[K_];
#pragma unroll
    for (int k = 0; k < K_; k++) {
        wreg[k] = wlist[k];
        oreg[k] = cilist[k] * 15 + cjlist[k];
    }
    float* op = outp + (size_t)bq * D_;
    for (int dI = tid; dI < D_; dI += 192) {
        int rs = dI >> 4, c = dI & 15;
        int r = rs / 7, s = rs % 7;
        const float* Gb = &Gl[c * PLS + r * 15 + s];
        float acc = 0.f;
#pragma unroll
        for (int k = 0; k < K_; k++) acc += wreg[k] * Gb[oreg[k]];
        op[dI] = acc;
    }
}

// ---------------------------------------------------------------------------
// K3: 1152 blocks x 256 threads; block = 32 pixels.
//  P1: 128 threads = (px, contrib): gather 4x float4 from outp (contiguous).
//  P1b: reduce 4 contribs, scale by analytic 1/(ni*nj) -> agg_l.
//  P2: (co-group, px): 16->64 conv from LDS weights + bias + residual.
// ---------------------------------------------------------------------------
__global__ __launch_bounds__(256) void output_kernel(
    const float* __restrict__ vid, const float* __restrict__ outp,
    const float* __restrict__ ww, const float* __restrict__ wb,
    float* __restrict__ out)
{
    __shared__ float part[32][4][CI_];   // 8 KB
    __shared__ float agg_l[32][17];      // padded stride 17
    __shared__ float w_l[C_ * CI_];      // 4 KB
    __shared__ float b_l[C_];

    int tid = threadIdx.x;
    *(float4*)&w_l[tid * 4] = *(const float4*)&ww[tid * 4];   // 1024 floats
    if (tid < C_) b_l[tid] = wb[tid];

    int gp0 = blockIdx.x * 32;

    if (tid < 128) {
        int px = tid >> 2, cb = tid & 3;
        int idx = gp0 + px;
        int n = idx / HW_, pix = idx % HW_;
        int y = pix / W__, x = pix % W__;
        int thi_i = min(nH_ - 1, (y + PP_) >> 2);
        int thi_j = min(nH_ - 1, (x + PP_) >> 2);
        int qi = (y >> 2) + (cb >> 1);
        int qj = (x >> 2) + (cb & 1);
        float4 r0 = make_float4(0.f, 0.f, 0.f, 0.f), r1 = r0, r2 = r0, r3 = r0;
        if (qi <= thi_i && qj <= thi_j) {
            int a  = y + PP_ - S0_ * qi;          // 0..6
            int bb = x + PP_ - S0_ * qj;          // 0..6
            const float* op = outp +
                (((size_t)n * NQ_ + qi * nH_ + qj) * 49 + a * 7 + bb) * CI_;
            r0 = *(const float4*)&op[0];
            r1 = *(const float4*)&op[4];
            r2 = *(const float4*)&op[8];
            r3 = *(const float4*)&op[12];
        }
        *(float4*)&part[px][cb][0]  = r0;
        *(float4*)&part[px][cb][4]  = r1;
        *(float4*)&part[px][cb][8]  = r2;
        *(float4*)&part[px][cb][12] = r3;
    }
    __syncthreads();

    {
        int px = tid >> 3, c2 = (tid & 7) * 2;
        int idx = gp0 + px;
        int pix = idx % HW_;
        int y = pix / W__, x = pix % W__;
        int ni = min(nH_ - 1, (y + PP_) >> 2) - (y >> 2) + 1;
        int nj = min(nH_ - 1, (x + PP_) >> 2) - (x >> 2) + 1;
        float inv = 1.f / (float)(ni * nj);
#pragma unroll
        for (int k = 0; k < 2; k++) {
            int c = c2 + k;
            agg_l[px][c] = (part[px][0][c] + part[px][1][c] +
                            part[px][2][c] + part[px][3][c]) * inv;
        }
    }
    __syncthreads();

    int og = tid >> 5, px = tid & 31;
    int idx = gp0 + px;
    int n = idx / HW_, pix = idx % HW_;
    float ar[CI_];
#pragma unroll
    for (int c = 0; c < CI_; c++) ar[c] = agg_l[px][c];

    const float* vp  = vid + (size_t)n * C_ * HW_ + pix;
    float*       op2 = out + (size_t)n * C_ * HW_ + pix;
#pragma unroll
    for (int o = 0; o < 8; o++) {
        int co = og * 8 + o;
        float4 w0 = *(const float4*)&w_l[co * CI_ + 0];
        float4 w1 = *(const float4*)&w_l[co * CI_ + 4];
        float4 w2 = *(const float4*)&w_l[co * CI_ + 8];
        float4 w3 = *(const float4*)&w_l[co * CI_ + 12];
        float s = b_l[co];
        s += w0.x * ar[0]  + w0.y * ar[1]  + w0.z * ar[2]  + w0.w * ar[3];
        s += w1.x * ar[4]  + w1.y * ar[5]  + w1.z * ar[6]  + w1.w * ar[7];
        s += w2.x * ar[8]  + w2.y * ar[9]  + w2.z * ar[10] + w2.w * ar[11];
        s += w3.x * ar[12] + w3.y * ar[13] + w3.z * ar[14] + w3.w * ar[15];
        op2[(size_t)co * HW_] = vp[(size_t)co * HW_] + s;
    }
}

// ---------------------------------------------------------------------------
extern "C" void kernel_launch(void* const* d_in, const int* in_sizes, int n_in,
                              void* d_out, int out_size, void* d_ws, size_t ws_size,
                              hipStream_t stream) {
    const float* vid   = (const float*)d_in[0];
    const int*   flows = (const int*)  d_in[1];
    const float* tw    = (const float*)d_in[2];
    const float* tb    = (const float*)d_in[3];
    const float* pw    = (const float*)d_in[4];
    const float* pb    = (const float*)d_in[5];
    const float* gw    = (const float*)d_in[6];
    const float* gb    = (const float*)d_in[7];
    const float* ww    = (const float*)d_in[8];
    const float* wb    = (const float*)d_in[9];
    float* out = (float*)d_out;

    float* ws = (float*)d_ws;
    const size_t fsz = (size_t)N_ * HW_ * CI_;          // 589,824 floats each
    float* theta = ws;
    float* phi   = ws + fsz;
    float* g     = ws + 2 * fsz;
    float* outp  = ws + 3 * fsz;                        // N*NQ*784 floats

    conv_kernel<<<864, 256, 0, stream>>>(
        vid, tw, tb, pw, pb, gw, gb, theta, phi, g);
    attn_kernel<<<N_ * NQ_, 192, 0, stream>>>(theta, phi, g, flows, outp);
    output_kernel<<<1152, 256, 0, stream>>>(vid, outp, ww, wb, out);
}